// Round 7
// baseline (307.576 us; speedup 1.0000x reference)
//
#include <hip/hip_runtime.h>

typedef __bf16 bf16_t;
typedef __bf16 bf16x8 __attribute__((ext_vector_type(8)));
typedef float f32x16 __attribute__((ext_vector_type(16)));

#define CTOT 320
#define NPIX 32768  // 8*64*64

#define SPLANE_U 6544   // (12*68*8)+16 pad
#define SPLANE_M 5776   // (20*36*8)+16 pad
// Sw region starts after 2 Sin planes; 13 slots x 1024 el (reused by tap groups A/B)
// S total = 2*6544 + 13*1024 = 26400 el = 52800 B

// ---------- P1: y [b][c][h][w] f32 -> yt [pix][320] bf16 (dense, pixel-major)
// ----------                       -> ytp [packed even-checkerboard pix][320]
__global__ __launch_bounds__(256) void k_transpose_y(const float* __restrict__ y,
                                                     bf16_t* __restrict__ yt,
                                                     bf16_t* __restrict__ ytp) {
  __shared__ bf16_t T[64][72];
  int blk = blockIdx.x;            // (8*64) * 5 blocks
  int c0 = (blk % 5) * 64;
  int bh = blk / 5;                // b*64 + h
  int b = bh >> 6, h = bh & 63;
  int tid = threadIdx.x;
  {
    int c = tid >> 2, w0 = (tid & 3) << 4;
    const float* src = y + (size_t)(b * CTOT + c0 + c) * 4096 + (h << 6) + w0;
#pragma unroll
    for (int j = 0; j < 16; j += 4) {
      float4 v = *(const float4*)(src + j);
      T[c][w0 + j + 0] = (bf16_t)v.x;
      T[c][w0 + j + 1] = (bf16_t)v.y;
      T[c][w0 + j + 2] = (bf16_t)v.z;
      T[c][w0 + j + 3] = (bf16_t)v.w;
    }
  }
  __syncthreads();
  {
    int w = tid >> 2, cq = (tid & 3) << 4;
    union { uint4 v; bf16_t b[8]; } u0, u1;
#pragma unroll
    for (int j = 0; j < 8; ++j) { u0.b[j] = T[cq + j][w]; u1.b[j] = T[cq + 8 + j][w]; }
    bf16_t* dst = yt + (size_t)((bh << 6) | w) * CTOT + c0 + cq;
    *(uint4*)dst = u0.v;
    *(uint4*)(dst + 8) = u1.v;
  }
  if (tid < 128) {  // packed copy: w = 2j + (h&1)  (even checkerboard)
    int j = tid >> 2, cq = (tid & 3) << 4;
    int w = (j << 1) + (h & 1);
    union { uint4 v; bf16_t b[8]; } u0, u1;
#pragma unroll
    for (int k = 0; k < 8; ++k) { u0.b[k] = T[cq + k][w]; u1.b[k] = T[cq + 8 + k][w]; }
    bf16_t* dst = ytp + (size_t)((bh << 5) + j) * CTOT + c0 + cq;
    *(uint4*)dst = u0.v;
    *(uint4*)(dst + 8) = u1.v;
  }
}

// ---------- P2: w [oc][ic][5][5] f32 -> wt [tap][OCp][IC] bf16 (oc zero-padded)
__global__ __launch_bounds__(256) void k_transpose_w(const float* __restrict__ w,
                                                     bf16_t* __restrict__ wt,
                                                     int IC, int OC, int OCp) {
  int idx = blockIdx.x * 256 + threadIdx.x;
  if (idx >= OCp * IC) return;
  int oc = idx / IC, ic = idx - oc * IC;
  bool valid = (oc < OC);
  const float* src = w + (size_t)(oc * IC + ic) * 25;
#pragma unroll
  for (int t = 0; t < 25; ++t) {
    float v = valid ? src[t] : 0.0f;
    wt[(size_t)(t * OCp + oc) * IC + ic] = (bf16_t)v;
  }
}

// ---------- main: implicit-GEMM conv, 32x32x16 MFMA, K-chunk=16,
// T14 async-stage: issue global->reg early, ds_write late; taps split A/B.
struct ConvDesc {
  const float* bias;
  int out_off, wt_off;
  int ICp, OC, OCp, chs, masked, job_start;
};
struct MainParams {
  const bf16_t* yt;
  const bf16_t* ytp;
  const bf16_t* wt;
  float* out;
  ConvDesc cv[9];
};

template <bool MASKED>
__device__ __forceinline__ void conv_run(const ConvDesc cd, const MainParams& P,
                                         int local, bf16_t* S) {
  constexpr int NT  = MASKED ? 12 : 25;
  constexpr int NTA = MASKED ? 6 : 13;
  constexpr int NTB = NT - NTA;                  // 6 / 12
  constexpr int SWOFF_T = 2 * (MASKED ? SPLANE_M : SPLANE_U);
  constexpr int NSIN = MASKED ? 1360 : 1632;     // staging tasks (uint4 each)
  constexpr int ISIN = (NSIN + 511) / 512;       // 3 / 4
  constexpr int ISWA = (NTA * 128 + 511) / 512;  // 2 / 4
  constexpr int ISWB = (NTB * 128 + 511) / 512;  // 2 / 3

  int mb = MASKED ? (local >> 5) : (local >> 6);
  int nb = local & (MASKED ? 31 : 63);
  int b  = MASKED ? (nb >> 2) : (nb >> 3);
  int hblk = MASKED ? ((nb & 3) << 4) : ((nb & 7) << 3);
  int tid = threadIdx.x;
  int lane = tid & 63, wn = tid >> 6;
  int l31 = lane & 31, kq = lane >> 5;

  int octmax = (cd.OC - (mb << 6)) >> 5; if (octmax > 2) octmax = 2;

  f32x16 acc00 = {}, acc01 = {}, acc10 = {}, acc11 = {};

  int aoff = SWOFF_T + kq * 512 + l31 * 8;
  int boff = MASKED ? (kq * SPLANE_M + ((wn << 1) * 36 + 1 + l31) * 8)
                    : (kq * SPLANE_U + (wn * 68 + l31) * 8);

  const bf16_t* wtc = P.wt + cd.wt_off;
  int nchunks = cd.ICp >> 4;

  uint4 rin[ISIN], rwa[ISWA], rwb[ISWB];

  // task -> (dst, src, inb) for Sin staging (addresses recomputed to save VGPRs)
  auto sin_task = [&](int t, int& dst, const bf16_t*& src, bool& inb) {
    if (!MASKED) {
      int rr = t / 136, rem = t - rr * 136, cc = rem >> 1, icg = rem & 1;
      int h = hblk + rr - 2, w = cc - 2;
      inb = (((unsigned)h < 64u) & ((unsigned)w < 64u)) != 0;
      dst = icg * SPLANE_U + (rr * 68 + cc) * 8;
      int hh = inb ? h : 0, ww = inb ? w : 0;
      src = P.yt + (size_t)((((b << 6) + hh) << 6) | ww) * CTOT + cd.chs + (icg << 3);
    } else {
      int rr = t / 68, rem = t - rr * 68, cc = rem >> 1, icg = rem & 1;
      int h = hblk + rr - 2, j = cc - 1;
      inb = (((unsigned)h < 64u) & ((unsigned)j < 32u)) != 0;
      dst = icg * SPLANE_M + (rr * 36 + cc) * 8;
      int hh = inb ? h : 0, jj = inb ? j : 0;
      src = P.ytp + (size_t)((((b << 6) + hh) << 5) + jj) * CTOT + cd.chs + (icg << 3);
    }
  };
  auto sw_task = [&](int t, bool grpB, int& dst, int& srcoff) {
    int slot = t >> 7, rem = t & 127, oc = rem >> 1, icg = rem & 1;
    int tidx = slot + (grpB ? NTA : 0);
    int tap = MASKED ? (2 * tidx + 1) : tidx;
    dst = SWOFF_T + slot * 1024 + icg * 512 + oc * 8;
    srcoff = (tap * cd.OCp + (mb << 6) + oc) * cd.ICp + (icg << 3);
  };

  auto issue_sina = [&](int ic0) {
#pragma unroll
    for (int i = 0; i < ISIN; ++i) {
      int t = i * 512 + tid;
      bool tv = (t < NSIN);
      int dst; const bf16_t* src; bool inb;
      sin_task(tv ? t : 0, dst, src, inb);
      if (tv && inb) rin[i] = *(const uint4*)(src + ic0);
    }
#pragma unroll
    for (int i = 0; i < ISWA; ++i) {
      int t = i * 512 + tid;
      bool tv = (t < NTA * 128);
      int dst, srcoff;
      sw_task(tv ? t : 0, false, dst, srcoff);
      if (tv) rwa[i] = *(const uint4*)(wtc + srcoff + ic0);
    }
  };
  auto commit_sina = [&]() {
    const uint4 z = {0u, 0u, 0u, 0u};
#pragma unroll
    for (int i = 0; i < ISIN; ++i) {
      int t = i * 512 + tid;
      bool tv = (t < NSIN);
      int dst; const bf16_t* src; bool inb;
      sin_task(tv ? t : 0, dst, src, inb);
      if (tv) *(uint4*)(S + dst) = inb ? rin[i] : z;
    }
#pragma unroll
    for (int i = 0; i < ISWA; ++i) {
      int t = i * 512 + tid;
      bool tv = (t < NTA * 128);
      int dst, srcoff;
      sw_task(tv ? t : 0, false, dst, srcoff);
      if (tv) *(uint4*)(S + dst) = rwa[i];
    }
  };
  auto issue_b = [&](int ic0) {
#pragma unroll
    for (int i = 0; i < ISWB; ++i) {
      int t = i * 512 + tid;
      bool tv = (t < NTB * 128);
      int dst, srcoff;
      sw_task(tv ? t : 0, true, dst, srcoff);
      if (tv) rwb[i] = *(const uint4*)(wtc + srcoff + ic0);
    }
  };
  auto commit_b = [&]() {
#pragma unroll
    for (int i = 0; i < ISWB; ++i) {
      int t = i * 512 + tid;
      bool tv = (t < NTB * 128);
      int dst, srcoff;
      sw_task(tv ? t : 0, true, dst, srcoff);
      if (tv) *(uint4*)(S + dst) = rwb[i];
    }
  };

  // NOTE: plain ints (not constexpr) — loops below are fully unrolled with
  // compile-time trip counts, so these fold to constants. Masked j0/j1
  // numerators are provably even (tap parity), so runtime int division is exact.
#define TAP_ONE(S_, TAPIDX)                                                     \
  {                                                                             \
    int tap_ = MASKED ? (2 * (TAPIDX) + 1) : (TAPIDX);                          \
    int dy_ = tap_ / 5, dx_ = tap_ % 5;                                         \
    bf16x8 af0 = *(const bf16x8*)(S + aoff + (S_) * 1024);                      \
    bf16x8 bf0, bf1;                                                            \
    if (!MASKED) {                                                              \
      int toff_ = (dy_ * 68 + dx_) * 8;                                         \
      bf0 = *(const bf16x8*)(S + boff + toff_);                                 \
      bf1 = *(const bf16x8*)(S + boff + toff_ + 256);                           \
    } else {                                                                    \
      int j0_ = (dx_ - 1 - (dy_ & 1)) / 2;                                      \
      int j1_ = (dx_ - 2 - ((dy_ + 1) & 1)) / 2;                                \
      bf0 = *(const bf16x8*)(S + boff + (dy_ * 36 + j0_) * 8);                  \
      bf1 = *(const bf16x8*)(S + boff + ((dy_ + 1) * 36 + j1_) * 8);            \
    }                                                                           \
    acc00 = __builtin_amdgcn_mfma_f32_32x32x16_bf16(af0, bf0, acc00, 0, 0, 0);  \
    acc01 = __builtin_amdgcn_mfma_f32_32x32x16_bf16(af0, bf1, acc01, 0, 0, 0);  \
    if (octmax > 1) {                                                           \
      bf16x8 af1 = *(const bf16x8*)(S + aoff + (S_) * 1024 + 256);              \
      acc10 = __builtin_amdgcn_mfma_f32_32x32x16_bf16(af1, bf0, acc10, 0, 0, 0);\
      acc11 = __builtin_amdgcn_mfma_f32_32x32x16_bf16(af1, bf1, acc11, 0, 0, 0);\
    }                                                                           \
  }

  issue_sina(0);
  for (int cb = 0; cb < nchunks; ++cb) {
    int ic0 = cb << 4;
    if (cb) __syncthreads();      // waves done reading prev chunk's Sin/Sw(B)
    commit_sina();
    __syncthreads();
    issue_b(ic0);                 // SwB loads fly under tapsA
#pragma unroll
    for (int s = 0; s < NTA; ++s) TAP_ONE(s, s);
    __syncthreads();              // tapsA done reading Sw slots
    commit_b();
    __syncthreads();
    if (cb + 1 < nchunks) issue_sina(ic0 + 16);  // next chunk flies under tapsB
#pragma unroll
    for (int s = 0; s < NTB; ++s) TAP_ONE(s, s + NTA);
  }
#undef TAP_ONE

  // ---- epilogue: bias (+ parity packing for masked) ----
  float* outp = P.out + cd.out_off;
#define EPI_U(A, OT, PT)                                                        \
  {                                                                             \
    int h = hblk + wn;                                                          \
    _Pragma("unroll")                                                           \
    for (int r = 0; r < 16; ++r) {                                              \
      int row = (r & 3) + ((r >> 2) << 3) + (kq << 2);                          \
      int oc = (mb << 6) + ((OT) << 5) + row;                                   \
      outp[(size_t)(b * cd.OC + oc) * 4096 + (h << 6) + ((PT) << 5) + l31] =    \
          (A)[r] + cd.bias[oc];                                                 \
    }                                                                           \
  }
#define EPI_M(A, OT, PT)                                                        \
  {                                                                             \
    int h = hblk + (wn << 1) + (PT);                                            \
    _Pragma("unroll")                                                           \
    for (int r = 0; r < 16; ++r) {                                              \
      int row = (r & 3) + ((r >> 2) << 3) + (kq << 2);                          \
      int oc = (mb << 6) + ((OT) << 5) + row;                                   \
      float val = (A)[r] + cd.bias[oc];                                         \
      float2 pr;                                                                \
      if ((PT) == 0) { pr.x = 0.0f; pr.y = val; }                               \
      else           { pr.x = val;  pr.y = 0.0f; }                              \
      *(float2*)(outp + (size_t)(b * cd.OC + oc) * 4096 + (h << 6) + (l31 << 1)) = pr; \
    }                                                                           \
  }
  if (!MASKED) {
    EPI_U(acc00, 0, 0); EPI_U(acc01, 0, 1);
    if (octmax > 1) { EPI_U(acc10, 1, 0); EPI_U(acc11, 1, 1); }
  } else {
    EPI_M(acc00, 0, 0); EPI_M(acc01, 0, 1);
    if (octmax > 1) { EPI_M(acc10, 1, 0); EPI_M(acc11, 1, 1); }
  }
#undef EPI_U
#undef EPI_M
}

__global__ __launch_bounds__(512, 4) void k_conv_main(MainParams P) {
  __shared__ bf16_t S[26400];   // 52800 B: Sin (2 planes) + Sw (13 slots)
  int bid = blockIdx.x;
  int ci = 0;
#pragma unroll
  for (int i = 1; i < 9; ++i) if (bid >= P.cv[i].job_start) ci = i;
  ConvDesc cd = P.cv[ci];
  int local = bid - cd.job_start;
  if (cd.masked) conv_run<true>(cd, P, local, S);
  else           conv_run<false>(cd, P, local, S);
}

extern "C" void kernel_launch(void* const* d_in, const int* in_sizes, int n_in,
                              void* d_out, int out_size, void* d_ws, size_t ws_size,
                              hipStream_t stream) {
  const float* y = (const float*)d_in[0];
  bf16_t* yt  = (bf16_t*)d_ws;                               // 10,485,760 el
  bf16_t* ytp = yt + (size_t)NPIX * CTOT;                    // +5,242,880 el
  bf16_t* wt  = ytp + (size_t)(NPIX / 2) * CTOT;             // +3,660,800 el (~37 MB total)

  k_transpose_y<<<2560, 256, 0, stream>>>(y, yt, ytp);

  // Heaviest-first:      ch4      sp4     ch3     ch2     ch1     sp3     sp2     sp1    sp0
  static const int ICv[9]  = {128,    192,    64,     32,     16,     64,     32,     16,    16};
  static const int OCv[9]  = {384,    384,    128,    64,     32,     128,    64,     32,    32};
  static const int OCp[9]  = {384,    384,    128,    64,     64,     128,    64,     64,    64};
  static const int WIDX[9] = {19,     11,     17,     15,     13,     9,      7,      5,     3};
  static const int BIDX[9] = {20,     12,     18,     16,     14,     10,     8,      6,     4};
  static const int CHS[9]  = {0,      128,    0,      0,      0,      64,     32,     16,    0};
  static const int MSK[9]  = {0,      1,      0,      0,      0,      1,      1,      1,     1};
  static const int WTOFF[9] = {0, 1228800, 3072000, 3276800, 3328000,
                               3353600, 3558400, 3609600, 3635200};
  static const int OUTOFF[9] = {28311552, 15728640, 11534336, 5242880, 2097152,
                                7340032,  3145728,  1048576,  0};
  static const int JOBST[9] = {0, 384, 576, 704, 768, 832, 896, 928, 960};  // total 992

  for (int i = 0; i < 9; ++i) {
    int n = OCp[i] * ICv[i];
    k_transpose_w<<<(n + 255) / 256, 256, 0, stream>>>(
        (const float*)d_in[WIDX[i]], wt + WTOFF[i], ICv[i], OCv[i], OCp[i]);
  }

  MainParams P;
  P.yt = yt; P.ytp = ytp; P.wt = wt; P.out = (float*)d_out;
  for (int i = 0; i < 9; ++i) {
    P.cv[i].bias = (const float*)d_in[BIDX[i]];
    P.cv[i].out_off = OUTOFF[i];
    P.cv[i].wt_off = WTOFF[i];
    P.cv[i].ICp = ICv[i]; P.cv[i].OC = OCv[i]; P.cv[i].OCp = OCp[i];
    P.cv[i].chs = CHS[i]; P.cv[i].masked = MSK[i];
    P.cv[i].job_start = JOBST[i];
  }
  k_conv_main<<<992, 512, 0, stream>>>(P);
}

// Round 8
// 207.125 us; speedup vs baseline: 1.4850x; 1.4850x over previous
//
#include <hip/hip_runtime.h>

typedef __bf16 bf16_t;
typedef __bf16 bf16x8 __attribute__((ext_vector_type(8)));
typedef float f32x16 __attribute__((ext_vector_type(16)));
typedef unsigned int u32;

#define CTOT 320
#define NPIX 32768  // 8*64*64

// global -> LDS direct DMA, 16 B per lane; LDS dest = wave-uniform base + lane*16
__device__ __forceinline__ void gload16(const void* g, void* l) {
  __builtin_amdgcn_global_load_lds((const __attribute__((address_space(1))) u32*)g,
                                   (__attribute__((address_space(3))) u32*)l, 16, 0, 0);
}

// ---------- P1: y [b][c][h][w] f32 -> yt [pix][320] bf16 (dense, pixel-major)
// ----------                       -> ytp [packed even-checkerboard pix][320]
__global__ __launch_bounds__(256) void k_transpose_y(const float* __restrict__ y,
                                                     bf16_t* __restrict__ yt,
                                                     bf16_t* __restrict__ ytp) {
  __shared__ bf16_t T[64][72];
  int blk = blockIdx.x;            // (8*64) * 5 blocks
  int c0 = (blk % 5) * 64;
  int bh = blk / 5;                // b*64 + h
  int b = bh >> 6, h = bh & 63;
  int tid = threadIdx.x;
  {
    int c = tid >> 2, w0 = (tid & 3) << 4;
    const float* src = y + (size_t)(b * CTOT + c0 + c) * 4096 + (h << 6) + w0;
#pragma unroll
    for (int j = 0; j < 16; j += 4) {
      float4 v = *(const float4*)(src + j);
      T[c][w0 + j + 0] = (bf16_t)v.x;
      T[c][w0 + j + 1] = (bf16_t)v.y;
      T[c][w0 + j + 2] = (bf16_t)v.z;
      T[c][w0 + j + 3] = (bf16_t)v.w;
    }
  }
  __syncthreads();
  {
    int w = tid >> 2, cq = (tid & 3) << 4;
    union { uint4 v; bf16_t b[8]; } u0, u1;
#pragma unroll
    for (int j = 0; j < 8; ++j) { u0.b[j] = T[cq + j][w]; u1.b[j] = T[cq + 8 + j][w]; }
    bf16_t* dst = yt + (size_t)((bh << 6) | w) * CTOT + c0 + cq;
    *(uint4*)dst = u0.v;
    *(uint4*)(dst + 8) = u1.v;
  }
  if (tid < 128) {  // packed copy: w = 2j + (h&1)  (even checkerboard)
    int j = tid >> 2, cq = (tid & 3) << 4;
    int w = (j << 1) + (h & 1);
    union { uint4 v; bf16_t b[8]; } u0, u1;
#pragma unroll
    for (int k = 0; k < 8; ++k) { u0.b[k] = T[cq + k][w]; u1.b[k] = T[cq + 8 + k][w]; }
    bf16_t* dst = ytp + (size_t)((bh << 5) + j) * CTOT + c0 + cq;
    *(uint4*)dst = u0.v;
    *(uint4*)(dst + 8) = u1.v;
  }
}

// ---------- P2: w [oc][ic][5][5] f32 -> wt [tap][icg][OCp][8] bf16 ----------
// (so a 64-lane DMA reads 1 KB contiguous: lane = oc)
__global__ __launch_bounds__(256) void k_transpose_w(const float* __restrict__ w,
                                                     bf16_t* __restrict__ wt,
                                                     int IC, int OC, int OCp) {
  int idx = blockIdx.x * 256 + threadIdx.x;
  if (idx >= OCp * IC) return;
  int oc = idx / IC, ic = idx - oc * IC;
  bool valid = (oc < OC);
  const float* src = w + (size_t)(oc * IC + ic) * 25;
  int icg = ic >> 3, ie = ic & 7;
#pragma unroll
  for (int t = 0; t < 25; ++t) {
    float v = valid ? src[t] : 0.0f;
    wt[(size_t)((t * (IC >> 3) + icg) * OCp + oc) * 8 + ie] = (bf16_t)v;
  }
}

__global__ void k_zero(uint4* z) { z[threadIdx.x] = uint4{0u, 0u, 0u, 0u}; }

// ---------- main: implicit-GEMM conv, 32x32x16 MFMA, K-chunk=16,
// double-buffered Sin+Sw staged via global_load_lds DMA; 1 barrier per chunk.
struct ConvDesc {
  const float* bias;
  int out_off, wt_off;
  int ICp, OC, OCp, chs, masked, job_start;
};
struct MainParams {
  const bf16_t* yt;
  const bf16_t* ytp;
  const bf16_t* wt;
  const bf16_t* zp;   // 1 KB of zeros (DMA source for halo/pad)
  float* out;
  ConvDesc cv[9];
};

template <bool MASKED>
__device__ __forceinline__ void conv_run(const ConvDesc cd, const MainParams& P,
                                         int local, bf16_t* S) {
  constexpr int NT   = MASKED ? 12 : 25;
  constexpr int COLS = MASKED ? 36 : 68;
  constexpr int REAL = MASKED ? 720 : 816;   // real slots per plane
  constexpr int NSG  = MASKED ? 12 : 13;     // 64-slot DMA groups per plane
  constexpr int SPL  = NSG * 512;            // plane stride (el)
  constexpr int SWO  = 2 * SPL;              // Sw offset within buffer
  constexpr int BUFSZ = SWO + NT * 1024;     // 24576 / 38912 el

  int mb = MASKED ? (local >> 5) : (local >> 6);
  int nb = local & (MASKED ? 31 : 63);
  int b  = MASKED ? (nb >> 2) : (nb >> 3);
  int hblk = MASKED ? ((nb & 3) << 4) : ((nb & 7) << 3);
  int tid = threadIdx.x, lane = tid & 63, wid = tid >> 6;
  int l31 = lane & 31, kq = lane >> 5;

  int octmax = (cd.OC - (mb << 6)) >> 5; if (octmax > 2) octmax = 2;

  f32x16 acc00 = {}, acc01 = {}, acc10 = {}, acc11 = {};

  int aofs = SWO + kq * 512 + l31 * 8;
  int bofs = kq * SPL + (MASKED ? (((wid << 1) * 36 + 1 + l31) * 8)
                                : ((wid * 68 + l31) * 8));

  const bf16_t* wtc = P.wt + cd.wt_off;
  int icgs = cd.ICp >> 3;
  int nchunks = cd.ICp >> 4;

  auto stage = [&](int cb, int buf) {
    int ic0 = cb << 4;
    bf16_t* Sb = S + buf * BUFSZ;
    // Sin: 2 planes (icg), NSG wave-groups each; lane -> slot, dest linear
    for (int g = wid; g < 2 * NSG; g += 8) {
      int p = (g >= NSG) ? 1 : 0;
      int gi = g - p * NSG;
      int s = (gi << 6) + lane;
      int rr = s / COLS, cc = s - rr * COLS;
      int h = hblk + rr - 2;
      const bf16_t* gp;
      if (!MASKED) {
        int w = cc - 2;
        bool inb = (s < REAL) && ((unsigned)h < 64u) && ((unsigned)w < 64u);
        gp = inb ? (P.yt + (size_t)((((b << 6) + (h & 63)) << 6) | (w & 63)) * CTOT
                        + cd.chs + ic0 + (p << 3))
                 : P.zp;
      } else {
        int j = cc - 1;
        bool inb = (s < REAL) && ((unsigned)h < 64u) && ((unsigned)j < 32u);
        gp = inb ? (P.ytp + (size_t)((((b << 6) + (h & 63)) << 5) + (j & 31)) * CTOT
                         + cd.chs + ic0 + (p << 3))
                 : P.zp;
      }
      gload16(gp, Sb + p * SPL + (gi << 9));
    }
    // Sw: 2*NT wave-groups; lane = oc, global 1 KB contiguous, dest linear
    for (int g = wid; g < 2 * NT; g += 8) {
      int slot = g >> 1, icg = g & 1;
      int tap = MASKED ? (2 * slot + 1) : slot;
      const bf16_t* gp = wtc +
          (size_t)((tap * icgs + (ic0 >> 3) + icg) * cd.OCp + (mb << 6) + lane) * 8;
      gload16(gp, Sb + SWO + (g << 9));
    }
  };

  stage(0, 0);
  for (int cb = 0; cb < nchunks; ++cb) {
    __syncthreads();                         // drains vmcnt: buf[cb&1] ready
    if (cb + 1 < nchunks) stage(cb + 1, (cb + 1) & 1);   // DMA flies under MFMA
    const bf16_t* Sb = S + (cb & 1) * BUFSZ;

#define TAP_ONE(TI)                                                             \
    {                                                                           \
      int tap_ = MASKED ? (2 * (TI) + 1) : (TI);                                \
      int dy_ = tap_ / 5, dx_ = tap_ % 5;                                       \
      bf16x8 af0 = *(const bf16x8*)(Sb + aofs + (TI) * 1024);                   \
      bf16x8 bf0, bf1;                                                          \
      if (!MASKED) {                                                            \
        int toff_ = (dy_ * 68 + dx_) * 8;                                       \
        bf0 = *(const bf16x8*)(Sb + bofs + toff_);                              \
        bf1 = *(const bf16x8*)(Sb + bofs + toff_ + 256);                        \
      } else {                                                                  \
        int j0_ = (dx_ - 1 - (dy_ & 1)) / 2;                                    \
        int j1_ = (dx_ - 2 - ((dy_ + 1) & 1)) / 2;                              \
        bf0 = *(const bf16x8*)(Sb + bofs + (dy_ * 36 + j0_) * 8);               \
        bf1 = *(const bf16x8*)(Sb + bofs + ((dy_ + 1) * 36 + j1_) * 8);         \
      }                                                                         \
      acc00 = __builtin_amdgcn_mfma_f32_32x32x16_bf16(af0, bf0, acc00, 0, 0, 0);\
      acc01 = __builtin_amdgcn_mfma_f32_32x32x16_bf16(af0, bf1, acc01, 0, 0, 0);\
      if (octmax > 1) {                                                         \
        bf16x8 af1 = *(const bf16x8*)(Sb + aofs + (TI) * 1024 + 256);           \
        acc10 = __builtin_amdgcn_mfma_f32_32x32x16_bf16(af1, bf0, acc10, 0,0,0);\
        acc11 = __builtin_amdgcn_mfma_f32_32x32x16_bf16(af1, bf1, acc11, 0,0,0);\
      }                                                                         \
    }
#pragma unroll
    for (int s = 0; s < NT; ++s) TAP_ONE(s)
#undef TAP_ONE
  }

  // ---- epilogue: bias (+ parity packing for masked) ----
  float* outp = P.out + cd.out_off;
#define EPI_U(A, OT, PT)                                                        \
  {                                                                             \
    int h = hblk + wid;                                                         \
    _Pragma("unroll")                                                           \
    for (int r = 0; r < 16; ++r) {                                              \
      int row = (r & 3) + ((r >> 2) << 3) + (kq << 2);                          \
      int oc = (mb << 6) + ((OT) << 5) + row;                                   \
      outp[(size_t)(b * cd.OC + oc) * 4096 + (h << 6) + ((PT) << 5) + l31] =    \
          (A)[r] + cd.bias[oc];                                                 \
    }                                                                           \
  }
#define EPI_M(A, OT, PT)                                                        \
  {                                                                             \
    int h = hblk + (wid << 1) + (PT);                                           \
    _Pragma("unroll")                                                           \
    for (int r = 0; r < 16; ++r) {                                              \
      int row = (r & 3) + ((r >> 2) << 3) + (kq << 2);                          \
      int oc = (mb << 6) + ((OT) << 5) + row;                                   \
      float val = (A)[r] + cd.bias[oc];                                         \
      float2 pr;                                                                \
      if ((PT) == 0) { pr.x = 0.0f; pr.y = val; }                               \
      else           { pr.x = val;  pr.y = 0.0f; }                              \
      *(float2*)(outp + (size_t)(b * cd.OC + oc) * 4096 + (h << 6) + (l31 << 1)) = pr; \
    }                                                                           \
  }
  if (!MASKED) {
    EPI_U(acc00, 0, 0); EPI_U(acc01, 0, 1);
    if (octmax > 1) { EPI_U(acc10, 1, 0); EPI_U(acc11, 1, 1); }
  } else {
    EPI_M(acc00, 0, 0); EPI_M(acc01, 0, 1);
    if (octmax > 1) { EPI_M(acc10, 1, 0); EPI_M(acc11, 1, 1); }
  }
#undef EPI_U
#undef EPI_M
}

__global__ __launch_bounds__(512, 2) void k_conv_main(MainParams P) {
  __shared__ bf16_t S[77824];   // 155648 B: 2 x (Sin 2 planes + Sw NT slots)
  int bid = blockIdx.x;
  int ci = 0;
#pragma unroll
  for (int i = 1; i < 9; ++i) if (bid >= P.cv[i].job_start) ci = i;
  ConvDesc cd = P.cv[ci];
  int local = bid - cd.job_start;
  if (cd.masked) conv_run<true>(cd, P, local, S);
  else           conv_run<false>(cd, P, local, S);
}

extern "C" void kernel_launch(void* const* d_in, const int* in_sizes, int n_in,
                              void* d_out, int out_size, void* d_ws, size_t ws_size,
                              hipStream_t stream) {
  const float* y = (const float*)d_in[0];
  bf16_t* yt  = (bf16_t*)d_ws;                               // 10,485,760 el
  bf16_t* ytp = yt + (size_t)NPIX * CTOT;                    // +5,242,880 el
  bf16_t* wt  = ytp + (size_t)(NPIX / 2) * CTOT;             // +3,660,800 el
  bf16_t* zp  = wt + 3660800;                                // +512 el (1 KB zeros)

  k_transpose_y<<<2560, 256, 0, stream>>>(y, yt, ytp);
  k_zero<<<1, 64, 0, stream>>>((uint4*)zp);

  // Heaviest-first:      ch4      sp4     ch3     ch2     ch1     sp3     sp2     sp1    sp0
  static const int ICv[9]  = {128,    192,    64,     32,     16,     64,     32,     16,    16};
  static const int OCv[9]  = {384,    384,    128,    64,     32,     128,    64,     32,    32};
  static const int OCp[9]  = {384,    384,    128,    64,     64,     128,    64,     64,    64};
  static const int WIDX[9] = {19,     11,     17,     15,     13,     9,      7,      5,     3};
  static const int BIDX[9] = {20,     12,     18,     16,     14,     10,     8,      6,     4};
  static const int CHS[9]  = {0,      128,    0,      0,      0,      64,     32,     16,    0};
  static const int MSK[9]  = {0,      1,      0,      0,      0,      1,      1,      1,     1};
  static const int WTOFF[9] = {0, 1228800, 3072000, 3276800, 3328000,
                               3353600, 3558400, 3609600, 3635200};
  static const int OUTOFF[9] = {28311552, 15728640, 11534336, 5242880, 2097152,
                                7340032,  3145728,  1048576,  0};
  static const int JOBST[9] = {0, 384, 576, 704, 768, 832, 896, 928, 960};  // total 992

  for (int i = 0; i < 9; ++i) {
    int n = OCp[i] * ICv[i];
    k_transpose_w<<<(n + 255) / 256, 256, 0, stream>>>(
        (const float*)d_in[WIDX[i]], wt + WTOFF[i], ICv[i], OCv[i], OCp[i]);
  }

  MainParams P;
  P.yt = yt; P.ytp = ytp; P.wt = wt; P.zp = zp; P.out = (float*)d_out;
  for (int i = 0; i < 9; ++i) {
    P.cv[i].bias = (const float*)d_in[BIDX[i]];
    P.cv[i].out_off = OUTOFF[i];
    P.cv[i].wt_off = WTOFF[i];
    P.cv[i].ICp = ICv[i]; P.cv[i].OC = OCv[i]; P.cv[i].OCp = OCp[i];
    P.cv[i].chs = CHS[i]; P.cv[i].masked = MSK[i];
    P.cv[i].job_start = JOBST[i];
  }
  k_conv_main<<<992, 512, 0, stream>>>(P);
}